// Round 8
// baseline (500.489 us; speedup 1.0000x reference)
//
#include <hip/hip_runtime.h>

// Problem constants
#define T_LEN 8192
#define DMODEL 1536
#define NH 16
#define NKV 4
#define HD 96
#define KVDIM (NKV * HD)   // 384
#define W2 256             // WINDOW/2
#define NFREQ 48           // HD/2
#define NGB 32             // global-attention split-k blocks per head

static constexpr float SCALE = 0.10206207261596577f; // 1/sqrt(96)

typedef float f32x4 __attribute__((ext_vector_type(4)));
typedef short short8 __attribute__((ext_vector_type(8)));
typedef unsigned short ushort;

__device__ __forceinline__ ushort f2bf(float f) {
  unsigned int x = __float_as_uint(f);
  return (ushort)((x + 0x7FFFu + ((x >> 16) & 1u)) >> 16);
}
__device__ __forceinline__ float bf2f(ushort u) {
  return __uint_as_float((unsigned int)u << 16);
}
__device__ __forceinline__ void load_lds16(const void* g, void* l) {
  __builtin_amdgcn_global_load_lds(
      (const __attribute__((address_space(1))) void*)g,
      (__attribute__((address_space(3))) void*)l, 16, 0, 0);
}

// ---------------------------------------------------------------------------
// Elementwise fp32 -> bf16
// ---------------------------------------------------------------------------
__global__ __launch_bounds__(256) void convert_bf16(
    const float* __restrict__ in, ushort* __restrict__ out, int n4) {
  const int i = blockIdx.x * 256 + threadIdx.x;
  if (i >= n4) return;
  const f32x4 v = *(const f32x4*)&in[i * 4];
  ushort o[4] = {f2bf(v[0]), f2bf(v[1]), f2bf(v[2]), f2bf(v[3])};
  *(unsigned long long*)&out[i * 4] =
      (unsigned long long)o[0] | ((unsigned long long)o[1] << 16) |
      ((unsigned long long)o[2] << 32) | ((unsigned long long)o[3] << 48);
}

// ---------------------------------------------------------------------------
// W[K][N] fp32 -> Wt[N][K] bf16 (single)
// ---------------------------------------------------------------------------
__global__ __launch_bounds__(256) void transpose_bf16(
    const float* __restrict__ W, ushort* __restrict__ Wt, int K, int N) {
  __shared__ ushort tile[32][33];
  const int tx = threadIdx.x & 31;
  const int ty = threadIdx.x >> 5;
  const int n0 = blockIdx.x * 32;
  const int k0 = blockIdx.y * 32;
#pragma unroll
  for (int i = 0; i < 32; i += 8)
    tile[tx][ty + i] = f2bf(W[(size_t)(k0 + ty + i) * N + n0 + tx]);
  __syncthreads();
#pragma unroll
  for (int i = 0; i < 32; i += 8)
    Wt[(size_t)(n0 + ty + i) * K + k0 + tx] = tile[ty + i][tx];
}

// Batched version for the 4 KV weights (z selects source).
// NOTE: parameter names must not collide with the W2 macro above!
__global__ __launch_bounds__(256) void transpose_bf16_kv4(
    const float* __restrict__ Wk, const float* __restrict__ Wv,
    const float* __restrict__ Wkg, const float* __restrict__ Wvg,
    ushort* __restrict__ Wt) {
  const int z = blockIdx.z;
  const float* W = (z == 0) ? Wk : (z == 1) ? Wv : (z == 2) ? Wkg : Wvg;
  ushort* dst = Wt + (size_t)z * KVDIM * DMODEL;
  __shared__ ushort tile[32][33];
  const int tx = threadIdx.x & 31;
  const int ty = threadIdx.x >> 5;
  const int n0 = blockIdx.x * 32;
  const int k0 = blockIdx.y * 32;
#pragma unroll
  for (int i = 0; i < 32; i += 8)
    tile[tx][ty + i] = f2bf(W[(size_t)(k0 + ty + i) * KVDIM + n0 + tx]);
  __syncthreads();
#pragma unroll
  for (int i = 0; i < 32; i += 8)
    dst[(size_t)(n0 + ty + i) * DMODEL + k0 + tx] = tile[ty + i][tx];
}

// ---------------------------------------------------------------------------
// bf16 [T][KVDIM] -> bf16 [KVDIM][T] (V pre-transpose for local attn)
// ---------------------------------------------------------------------------
__global__ __launch_bounds__(256) void transpose_u16(
    const ushort* __restrict__ in, ushort* __restrict__ out) {
  __shared__ ushort tile[32][33];
  const int tx = threadIdx.x & 31;
  const int ty = threadIdx.x >> 5;
  const int c0 = blockIdx.x * 32;   // dim
  const int r0 = blockIdx.y * 32;   // t
#pragma unroll
  for (int i = 0; i < 32; i += 8)
    tile[ty + i][tx] = in[(size_t)(r0 + ty + i) * KVDIM + c0 + tx];
  __syncthreads();
#pragma unroll
  for (int i = 0; i < 32; i += 8)
    out[(size_t)(c0 + ty + i) * T_LEN + r0 + tx] = tile[tx][ty + i];
}

// ---------------------------------------------------------------------------
// bf16 MFMA GEMM core body (m97 structure) shared by the variants below.
// ---------------------------------------------------------------------------
#define GEMM_BODY(KDIM, BT, ACC)                                              \
  __shared__ ushort Abuf[128 * 32];                                           \
  __shared__ ushort Bbuf[128 * 32];                                           \
  const int tid = threadIdx.x;                                                \
  const int wave = tid >> 6;                                                  \
  const int lane = tid & 63;                                                  \
  const int lo = lane & 15;                                                   \
  const int quad = lane >> 4;                                                 \
  const int m0 = blockIdx.y * 128;                                            \
  const int n0 = blockIdx.x * 128;                                            \
  const int mw = (wave & 1) * 64;                                             \
  const int nw = (wave >> 1) * 64;                                            \
  f32x4 ACC[4][4];                                                            \
  _Pragma("unroll") for (int i = 0; i < 4; ++i)                               \
      _Pragma("unroll") for (int j = 0; j < 4; ++j)                           \
          ACC[i][j] = {0.f, 0.f, 0.f, 0.f};                                   \
  for (int kt = 0; kt < (KDIM); kt += 32) {                                   \
    _Pragma("unroll") for (int j = 0; j < 2; ++j) {                           \
      const int c = wave * 128 + j * 64 + lane;                               \
      const int row = c >> 2;                                                 \
      const int colb = (c & 3) << 4;                                          \
      const int ldsOff = (wave * 128 + j * 64) * 16;                          \
      load_lds16((const char*)A + ((size_t)(m0 + row) * (KDIM) + kt) * 2 + colb, \
                 (char*)Abuf + ldsOff);                                       \
      load_lds16((const char*)(BT) + ((size_t)(n0 + row) * (KDIM) + kt) * 2 + colb, \
                 (char*)Bbuf + ldsOff);                                       \
    }                                                                         \
    __syncthreads();                                                          \
    short8 af[4], bfr[4];                                                     \
    _Pragma("unroll") for (int mt = 0; mt < 4; ++mt)                          \
        af[mt] = *(const short8*)&Abuf[(mw + mt * 16 + lo) * 32 + quad * 8];  \
    _Pragma("unroll") for (int nt = 0; nt < 4; ++nt)                          \
        bfr[nt] = *(const short8*)&Bbuf[(nw + nt * 16 + lo) * 32 + quad * 8]; \
    _Pragma("unroll") for (int mt = 0; mt < 4; ++mt)                          \
        _Pragma("unroll") for (int nt = 0; nt < 4; ++nt)                      \
            ACC[mt][nt] = __builtin_amdgcn_mfma_f32_16x16x32_bf16(            \
                af[mt], bfr[nt], ACC[mt][nt], 0, 0, 0);                       \
    __syncthreads();                                                          \
  }

// Plain fp32-out GEMM (used for W_o)
__global__ __launch_bounds__(256) void gemm_bf16(
    const ushort* __restrict__ A, const ushort* __restrict__ Bt,
    float* __restrict__ C, int N, int K) {
  GEMM_BODY(K, Bt, acc)
#pragma unroll
  for (int mt = 0; mt < 4; ++mt) {
    const int r0 = m0 + mw + mt * 16 + quad * 4;
#pragma unroll
    for (int nt = 0; nt < 4; ++nt) {
      const int cc = n0 + nw + nt * 16 + lo;
#pragma unroll
      for (int r = 0; r < 4; ++r)
        C[(size_t)(r0 + r) * N + cc] = acc[mt][nt][r];
    }
  }
}

// q projection with fused RoPE + bf16 store (N = DMODEL)
__global__ __launch_bounds__(256) void gemm_rope_q(
    const ushort* __restrict__ A, const ushort* __restrict__ Bt,
    ushort* __restrict__ Obf, const float* __restrict__ cosf,
    const float* __restrict__ sinf, const int* __restrict__ pid) {
  GEMM_BODY(DMODEL, Bt, acc)
#pragma unroll
  for (int mt = 0; mt < 4; ++mt) {
    const int r0 = m0 + mw + mt * 16 + quad * 4;
#pragma unroll
    for (int nt = 0; nt < 4; ++nt) {
      const int cc = n0 + nw + nt * 16 + lo;
      const int d = cc % HD;
      const int fi = d >> 1;
#pragma unroll
      for (int r = 0; r < 4; ++r) {
        const int t = r0 + r;
        float v = acc[mt][nt][r];
        const int pos = pid[t];
        const float co = cosf[(size_t)pos * NFREQ + fi];
        const float si = sinf[(size_t)pos * NFREQ + fi];
        const float pe = __shfl_xor(v, 1);
        v = (d & 1) ? fmaf(pe, si, v * co) : fmaf(v, co, -pe * si);
        Obf[(size_t)t * DMODEL + cc] = f2bf(v);
      }
    }
  }
}

// KV projections, z=0..3: z0 ksl(rope->bf16), z1 vsl(bf16), z2 kg(rope->f32),
// z3 vg(f32). N = KVDIM.
__global__ __launch_bounds__(256) void gemm_kv(
    const ushort* __restrict__ A, const ushort* __restrict__ BtPack,
    ushort* __restrict__ k_bf, ushort* __restrict__ v_bf,
    float* __restrict__ kg, float* __restrict__ vg,
    const float* __restrict__ cosf, const float* __restrict__ sinf,
    const int* __restrict__ pid) {
  const int z = blockIdx.z;
  const ushort* Bt = BtPack + (size_t)z * KVDIM * DMODEL;
  GEMM_BODY(DMODEL, Bt, acc)
  const bool doRope = (z == 0) || (z == 2);
#pragma unroll
  for (int mt = 0; mt < 4; ++mt) {
    const int r0 = m0 + mw + mt * 16 + quad * 4;
#pragma unroll
    for (int nt = 0; nt < 4; ++nt) {
      const int cc = n0 + nw + nt * 16 + lo;   // 0..383
      const int d = cc % HD;
      const int fi = d >> 1;
#pragma unroll
      for (int r = 0; r < 4; ++r) {
        const int t = r0 + r;
        float v = acc[mt][nt][r];
        if (doRope) {
          const int pos = pid[t];
          const float co = cosf[(size_t)pos * NFREQ + fi];
          const float si = sinf[(size_t)pos * NFREQ + fi];
          const float pe = __shfl_xor(v, 1);
          v = (d & 1) ? fmaf(pe, si, v * co) : fmaf(v, co, -pe * si);
        }
        const size_t idx = (size_t)t * KVDIM + cc;
        if (z == 0)      k_bf[idx] = f2bf(v);
        else if (z == 1) v_bf[idx] = f2bf(v);
        else if (z == 2) kg[idx] = v;
        else             vg[idx] = v;
      }
    }
  }
}

// ---------------------------------------------------------------------------
// qg row 0: zero + split-k atomics
// ---------------------------------------------------------------------------
__global__ void qg0_zero(float* __restrict__ qg0) {
  qg0[blockIdx.x * 256 + threadIdx.x] = 0.f;
}
__global__ __launch_bounds__(256) void qg0_split(
    const float* __restrict__ x, const float* __restrict__ W,
    float* __restrict__ qg0) {
  const int j = blockIdx.x * 256 + threadIdx.x;
  const int k0 = blockIdx.y * 128;
  float acc = 0.f;
#pragma unroll 8
  for (int k = k0; k < k0 + 128; ++k)
    acc = fmaf(x[k], W[(size_t)k * DMODEL + j], acc);
  atomicAdd(&qg0[j], acc);
}

// ---------------------------------------------------------------------------
// Local attention v4: MFMA bf16 flash tiles; V staged from pre-transposed
// Vt_g[KVDIM][T] via global_load_lds (no in-kernel transpose).
// ---------------------------------------------------------------------------
__global__ __launch_bounds__(256) void local_attn_v4(
    const ushort* __restrict__ qbf, const ushort* __restrict__ kbf,
    const ushort* __restrict__ vtg, const float* __restrict__ kg,
    const float* __restrict__ vg, ushort* __restrict__ obf) {
  __shared__ ushort Qb[3 * 64 * 32];
  __shared__ ushort Kb[3 * 64 * 32];
  __shared__ ushort Vt[2 * 96 * 32];   // panel kp: [96 dims][32 keys]
  __shared__ ushort Pb[4][2 * 16 * 32];
  __shared__ float Kg0[HD];
  __shared__ float Vg0[HD];

  const int t0 = blockIdx.x * 64;
  const int h  = blockIdx.y;
  const int kh = h >> 2;
  const int tid = threadIdx.x;
  const int w    = tid >> 6;
  const int lane = tid & 63;
  const int lo   = lane & 15;
  const int quad = lane >> 4;

  {
    const int rem = w * 64 + lane;
    const int row = rem >> 2;
    const int sub = (rem & 3) * 8;
#pragma unroll
    for (int j = 0; j < 3; ++j) {
      load_lds16(qbf + (size_t)(t0 + row) * DMODEL + h * HD + j * 32 + sub,
                 (char*)Qb + (j * 256 + w * 64) * 16);
    }
  }
  if (tid < HD) {
    Kg0[tid] = kg[kh * HD + tid];   // row 0 (rope at pos 0 = identity)
    Vg0[tid] = vg[kh * HD + tid];
  }

  f32x4 O[6];
#pragma unroll
  for (int i = 0; i < 6; ++i) O[i] = {0.f, 0.f, 0.f, 0.f};
  float m_run[4], l_run[4];
#pragma unroll
  for (int r = 0; r < 4; ++r) { m_run[r] = -1e30f; l_run[r] = 0.f; }

  __syncthreads();

  for (int ti = 0; ti < 5; ++ti) {
    const int kb = t0 - W2 + ti * 64;
    if (kb < 0) continue;

    {
      const int rem = w * 64 + lane;
      const int row = rem >> 2;
      const int sub = (rem & 3) * 8;
#pragma unroll
      for (int j = 0; j < 3; ++j) {
        load_lds16(kbf + (size_t)(kb + row) * KVDIM + kh * HD + j * 32 + sub,
                   (char*)Kb + (j * 256 + w * 64) * 16);
      }
      // V panels: chunk cc covers LDS bytes cc*16; cc = half*384 + d*4 + sub
#pragma unroll
      for (int j = 0; j < 3; ++j) {
        const int cc = j * 256 + w * 64 + lane;
        const int half = cc / 384;
        const int rm2 = cc - half * 384;
        const int dd = rm2 >> 2;
        const int sb = (rm2 & 3) * 8;
        load_lds16(vtg + (size_t)(kh * HD + dd) * T_LEN + kb + half * 32 + sb,
                   (char*)Vt + (j * 256 + w * 64) * 16);
      }
    }
    __syncthreads();

    short8 af[3];
#pragma unroll
    for (int p = 0; p < 3; ++p)
      af[p] = *(const short8*)&Qb[p * 2048 + (w * 16 + lo) * 32 + quad * 8];
    f32x4 s4[4];
#pragma unroll
    for (int nt = 0; nt < 4; ++nt) s4[nt] = {0.f, 0.f, 0.f, 0.f};
#pragma unroll
    for (int nt = 0; nt < 4; ++nt)
#pragma unroll
      for (int p = 0; p < 3; ++p) {
        const short8 bf8 =
            *(const short8*)&Kb[p * 2048 + (nt * 16 + lo) * 32 + quad * 8];
        s4[nt] = __builtin_amdgcn_mfma_f32_16x16x32_bf16(af[p], bf8, s4[nt], 0, 0, 0);
      }

    float alpha[4];
#pragma unroll
    for (int r = 0; r < 4; ++r) {
      const int tq = t0 + w * 16 + quad * 4 + r;
      float sv[4], rm = -1e30f;
#pragma unroll
      for (int nt = 0; nt < 4; ++nt) {
        const int p = kb + nt * 16 + lo;
        const bool ok = (p >= 1) && (p <= tq) && (p + W2 >= tq);
        sv[nt] = ok ? s4[nt][r] * SCALE : -1e30f;
        rm = fmaxf(rm, sv[nt]);
      }
#pragma unroll
      for (int mo = 1; mo < 16; mo <<= 1) rm = fmaxf(rm, __shfl_xor(rm, mo));
      const float m_new = fmaxf(m_run[r], rm);
      float psum = 0.f;
#pragma unroll
      for (int nt = 0; nt < 4; ++nt) {
        const float pv = (sv[nt] > -1e29f) ? __expf(sv[nt] - m_new) : 0.f;
        Pb[w][(nt >> 1) * 512 + (quad * 4 + r) * 32 + (nt & 1) * 16 + lo] = f2bf(pv);
        psum += pv;
      }
#pragma unroll
      for (int mo = 1; mo < 16; mo <<= 1) psum += __shfl_xor(psum, mo);
      alpha[r] = __expf(m_run[r] - m_new);
      l_run[r] = l_run[r] * alpha[r] + psum;
      m_run[r] = m_new;
    }

#pragma unroll
    for (int nt6 = 0; nt6 < 6; ++nt6)
#pragma unroll
      for (int r = 0; r < 4; ++r) O[nt6][r] *= alpha[r];

    short8 pa[2];
#pragma unroll
    for (int kp = 0; kp < 2; ++kp)
      pa[kp] = *(const short8*)&Pb[w][kp * 512 + lo * 32 + quad * 8];
#pragma unroll
    for (int nt6 = 0; nt6 < 6; ++nt6)
#pragma unroll
      for (int kp = 0; kp < 2; ++kp) {
        const short8 vb8 =
            *(const short8*)&Vt[kp * 3072 + (nt6 * 16 + lo) * 32 + quad * 8];
        O[nt6] = __builtin_amdgcn_mfma_f32_16x16x32_bf16(pa[kp], vb8, O[nt6], 0, 0, 0);
      }
    __syncthreads();
  }

  float sg[4];
#pragma unroll
  for (int r = 0; r < 4; ++r) {
    const int row = w * 16 + quad * 4 + r;
    float part = 0.f;
#pragma unroll
    for (int i = 0; i < 6; ++i) {
      const int d = lo * 6 + i;
      part += bf2f(Qb[(d >> 5) * 2048 + row * 32 + (d & 31)]) * Kg0[d];
    }
#pragma unroll
    for (int mo = 1; mo < 16; mo <<= 1) part += __shfl_xor(part, mo);
    sg[r] = part * SCALE;
  }
#pragma unroll
  for (int r = 0; r < 4; ++r) {
    const float m_new = fmaxf(m_run[r], sg[r]);
    const float al = __expf(m_run[r] - m_new);
    const float pg = __expf(sg[r] - m_new);
    const float inv = 1.0f / (l_run[r] * al + pg);
    ushort* dst = obf + (size_t)(t0 + w * 16 + quad * 4 + r) * DMODEL + h * HD;
#pragma unroll
    for (int nt6 = 0; nt6 < 6; ++nt6) {
      const int d = nt6 * 16 + lo;
      dst[d] = f2bf((O[nt6][r] * al + pg * Vg0[d]) * inv);
    }
  }
}

// ---------------------------------------------------------------------------
// Global row, split-k partials: grid (NH, NGB); 256 keys per block.
// ---------------------------------------------------------------------------
__global__ __launch_bounds__(256) void global_attn_part(
    const float* __restrict__ qg0, const float* __restrict__ kg,
    const float* __restrict__ vg, float* __restrict__ gM,
    float* __restrict__ gL, float* __restrict__ gO) {
  const int h = blockIdx.x;
  const int g = blockIdx.y;
  const int kh = h >> 2;
  const int tid = threadIdx.x;
  const int wv = tid >> 6;
  __shared__ float q[HD];
  __shared__ float sp[256];
  __shared__ float red[4];
  __shared__ float od[2][HD];

  if (tid < HD) q[tid] = qg0[h * HD + tid];
  __syncthreads();

  const int key = g * 256 + tid;
  const float* kp = kg + (size_t)key * KVDIM + kh * HD;
  float d = 0.f;
#pragma unroll
  for (int j = 0; j < 24; ++j) {
    const f32x4 kv = *(const f32x4*)(kp + j * 4);
    const f32x4 qv = *(const f32x4*)(&q[j * 4]);
    d += qv[0] * kv[0] + qv[1] * kv[1] + qv[2] * kv[2] + qv[3] * kv[3];
  }
  d *= SCALE;

  float pm = d;
#pragma unroll
  for (int off = 32; off > 0; off >>= 1) pm = fmaxf(pm, __shfl_down(pm, off));
  if ((tid & 63) == 0) red[wv] = pm;
  __syncthreads();
  const float M = fmaxf(fmaxf(red[0], red[1]), fmaxf(red[2], red[3]));
  __syncthreads();
  const float p = __expf(d - M);
  sp[tid] = p;
  float ps = p;
#pragma unroll
  for (int off = 32; off > 0; off >>= 1) ps += __shfl_down(ps, off);
  if ((tid & 63) == 0) red[wv] = ps;
  __syncthreads();
  const float L = red[0] + red[1] + red[2] + red[3];

  if (tid < 192) {
    const int grp = tid >= HD;
    const int dd = tid - grp * HD;
    float acc = 0.f;
    const float* vp = vg + (size_t)(g * 256 + grp * 128) * KVDIM + kh * HD + dd;
#pragma unroll 4
    for (int i = 0; i < 128; ++i)
      acc = fmaf(sp[grp * 128 + i], vp[(size_t)i * KVDIM], acc);
    od[grp][dd] = acc;
  }
  __syncthreads();
  if (tid < HD) gO[((size_t)h * NGB + g) * HD + tid] = od[0][tid] + od[1][tid];
  if (tid == 0) { gM[h * NGB + g] = M; gL[h * NGB + g] = L; }
}

__global__ void global_attn_comb(const float* __restrict__ gM,
                                 const float* __restrict__ gL,
                                 const float* __restrict__ gO,
                                 ushort* __restrict__ obf) {
  const int h = blockIdx.x;
  const int d = threadIdx.x;
  if (d >= HD) return;
  float M = -1e30f;
  for (int g = 0; g < NGB; ++g) M = fmaxf(M, gM[h * NGB + g]);
  float L = 0.f, O = 0.f;
  for (int g = 0; g < NGB; ++g) {
    const float e = __expf(gM[h * NGB + g] - M);
    L += gL[h * NGB + g] * e;
    O += gO[((size_t)h * NGB + g) * HD + d] * e;
  }
  obf[h * HD + d] = f2bf(O / L);
}

// ---------------------------------------------------------------------------
// Launch
// ---------------------------------------------------------------------------
extern "C" void kernel_launch(void* const* d_in, const int* in_sizes, int n_in,
                              void* d_out, int out_size, void* d_ws, size_t ws_size,
                              hipStream_t stream) {
  const float* x     = (const float*)d_in[0];
  const float* cosf  = (const float*)d_in[1];
  const float* sinf  = (const float*)d_in[2];
  const int*   pid   = (const int*)d_in[3];
  const float* W_qs  = (const float*)d_in[4];
  const float* W_ks  = (const float*)d_in[5];
  const float* W_vs  = (const float*)d_in[6];
  const float* W_qg  = (const float*)d_in[7];
  const float* W_kg  = (const float*)d_in[8];
  const float* W_vg  = (const float*)d_in[9];
  const float* W_o   = (const float*)d_in[10];
  float* out = (float*)d_out;

  char* p = (char*)d_ws;
  auto alloc = [&](size_t bytes) { char* r = p; p += (bytes + 255) & ~(size_t)255; return r; };
  float*  kg     = (float*)alloc((size_t)T_LEN * KVDIM * 4);
  float*  vg     = (float*)alloc((size_t)T_LEN * KVDIM * 4);
  float*  qg0    = (float*)alloc(DMODEL * 4);
  ushort* x_bf   = (ushort*)alloc((size_t)T_LEN * DMODEL * 2);
  ushort* q_bf   = (ushort*)alloc((size_t)T_LEN * DMODEL * 2);
  ushort* attnbf = (ushort*)alloc((size_t)T_LEN * DMODEL * 2);
  ushort* k_bf   = (ushort*)alloc((size_t)T_LEN * KVDIM * 2);
  ushort* v_bf   = (ushort*)alloc((size_t)T_LEN * KVDIM * 2);
  ushort* vt_g   = (ushort*)alloc((size_t)KVDIM * T_LEN * 2);
  ushort* Wqs_t  = (ushort*)alloc((size_t)DMODEL * DMODEL * 2);
  ushort* Wo_t   = (ushort*)alloc((size_t)DMODEL * DMODEL * 2);
  ushort* Wsml_t = (ushort*)alloc((size_t)4 * KVDIM * DMODEL * 2);
  float*  gM     = (float*)alloc((size_t)NH * NGB * 4);
  float*  gL     = (float*)alloc((size_t)NH * NGB * 4);
  float*  gO     = (float*)alloc((size_t)NH * NGB * HD * 4);

  const dim3 blk(256);
  const int nX4 = (T_LEN * DMODEL) / 4;

  // bf16 conversions / weight transposes
  convert_bf16<<<(nX4 + 255) / 256, blk, 0, stream>>>(x, x_bf, nX4);
  transpose_bf16<<<dim3(DMODEL / 32, DMODEL / 32), blk, 0, stream>>>(W_qs, Wqs_t, DMODEL, DMODEL);
  transpose_bf16<<<dim3(DMODEL / 32, DMODEL / 32), blk, 0, stream>>>(W_o,  Wo_t,  DMODEL, DMODEL);
  transpose_bf16_kv4<<<dim3(KVDIM / 32, DMODEL / 32, 4), blk, 0, stream>>>(
      W_ks, W_vs, W_kg, W_vg, Wsml_t);

  // Projections with fused RoPE/bf16 epilogues
  gemm_rope_q<<<dim3(DMODEL / 128, T_LEN / 128), blk, 0, stream>>>(
      x_bf, Wqs_t, q_bf, cosf, sinf, pid);
  gemm_kv<<<dim3(KVDIM / 128, T_LEN / 128, 4), blk, 0, stream>>>(
      x_bf, Wsml_t, k_bf, v_bf, kg, vg, cosf, sinf, pid);

  // qg row 0 (RoPE at pos 0 is identity -> skipped)
  qg0_zero<<<DMODEL / 256, blk, 0, stream>>>(qg0);
  qg0_split<<<dim3(DMODEL / 256, DMODEL / 128), blk, 0, stream>>>(x, W_qg, qg0);

  // V pre-transpose for local attention
  transpose_u16<<<dim3(KVDIM / 32, T_LEN / 32), blk, 0, stream>>>(v_bf, vt_g);

  // Attention
  local_attn_v4<<<dim3(T_LEN / 64, NH), blk, 0, stream>>>(
      q_bf, k_bf, vt_g, kg, vg, attnbf);
  global_attn_part<<<dim3(NH, NGB), blk, 0, stream>>>(qg0, kg, vg, gM, gL, gO);
  global_attn_comb<<<NH, dim3(128), 0, stream>>>(gM, gL, gO, attnbf);

  // Output projection
  gemm_bf16<<<dim3(DMODEL / 128, T_LEN / 128), blk, 0, stream>>>(
      attnbf, Wo_t, out, DMODEL, DMODEL);
}

// Round 9
// 464.139 us; speedup vs baseline: 1.0783x; 1.0783x over previous
//
#include <hip/hip_runtime.h>

// Problem constants
#define T_LEN 8192
#define DMODEL 1536
#define NH 16
#define NKV 4
#define HD 96
#define KVDIM (NKV * HD)   // 384
#define W2 256             // WINDOW/2
#define NFREQ 48           // HD/2
#define NGB 32             // global-attention split-k blocks per head
#define NPROJ 3072         // total projection output columns (q + k + v + kg + vg)

static constexpr float SCALE = 0.10206207261596577f; // 1/sqrt(96)

typedef float f32x4 __attribute__((ext_vector_type(4)));
typedef short short8 __attribute__((ext_vector_type(8)));
typedef unsigned short ushort;

__device__ __forceinline__ ushort f2bf(float f) {
  unsigned int x = __float_as_uint(f);
  return (ushort)((x + 0x7FFFu + ((x >> 16) & 1u)) >> 16);
}
__device__ __forceinline__ float bf2f(ushort u) {
  return __uint_as_float((unsigned int)u << 16);
}
__device__ __forceinline__ void load_lds16(const void* g, void* l) {
  __builtin_amdgcn_global_load_lds(
      (const __attribute__((address_space(1))) void*)g,
      (__attribute__((address_space(3))) void*)l, 16, 0, 0);
}

// ---------------------------------------------------------------------------
// Elementwise fp32 -> bf16
// ---------------------------------------------------------------------------
__global__ __launch_bounds__(256) void convert_bf16(
    const float* __restrict__ in, ushort* __restrict__ out, int n4) {
  const int i = blockIdx.x * 256 + threadIdx.x;
  if (i >= n4) return;
  const f32x4 v = *(const f32x4*)&in[i * 4];
  ushort o[4] = {f2bf(v[0]), f2bf(v[1]), f2bf(v[2]), f2bf(v[3])};
  *(unsigned long long*)&out[i * 4] =
      (unsigned long long)o[0] | ((unsigned long long)o[1] << 16) |
      ((unsigned long long)o[2] << 32) | ((unsigned long long)o[3] << 48);
}

// ---------------------------------------------------------------------------
// W[K][N] fp32 -> Wt[N][K] bf16 (single)
// ---------------------------------------------------------------------------
__global__ __launch_bounds__(256) void transpose_bf16(
    const float* __restrict__ W, ushort* __restrict__ Wt, int K, int N) {
  __shared__ ushort tile[32][33];
  const int tx = threadIdx.x & 31;
  const int ty = threadIdx.x >> 5;
  const int n0 = blockIdx.x * 32;
  const int k0 = blockIdx.y * 32;
#pragma unroll
  for (int i = 0; i < 32; i += 8)
    tile[tx][ty + i] = f2bf(W[(size_t)(k0 + ty + i) * N + n0 + tx]);
  __syncthreads();
#pragma unroll
  for (int i = 0; i < 32; i += 8)
    Wt[(size_t)(n0 + ty + i) * K + k0 + tx] = tile[ty + i][tx];
}

// Batched version for the 4 KV weights (z selects source).
// NOTE: parameter names must not collide with the W2 macro above!
__global__ __launch_bounds__(256) void transpose_bf16_kv4(
    const float* __restrict__ Wk, const float* __restrict__ Wv,
    const float* __restrict__ Wkg, const float* __restrict__ Wvg,
    ushort* __restrict__ Wt) {
  const int z = blockIdx.z;
  const float* W = (z == 0) ? Wk : (z == 1) ? Wv : (z == 2) ? Wkg : Wvg;
  ushort* dst = Wt + (size_t)z * KVDIM * DMODEL;
  __shared__ ushort tile[32][33];
  const int tx = threadIdx.x & 31;
  const int ty = threadIdx.x >> 5;
  const int n0 = blockIdx.x * 32;
  const int k0 = blockIdx.y * 32;
#pragma unroll
  for (int i = 0; i < 32; i += 8)
    tile[tx][ty + i] = f2bf(W[(size_t)(k0 + ty + i) * KVDIM + n0 + tx]);
  __syncthreads();
#pragma unroll
  for (int i = 0; i < 32; i += 8)
    dst[(size_t)(n0 + ty + i) * DMODEL + k0 + tx] = tile[ty + i][tx];
}

// ---------------------------------------------------------------------------
// bf16 [T][KVDIM] -> bf16 [KVDIM][T] (V pre-transpose for local attn)
// ---------------------------------------------------------------------------
__global__ __launch_bounds__(256) void transpose_u16(
    const ushort* __restrict__ in, ushort* __restrict__ out) {
  __shared__ ushort tile[32][33];
  const int tx = threadIdx.x & 31;
  const int ty = threadIdx.x >> 5;
  const int c0 = blockIdx.x * 32;   // dim
  const int r0 = blockIdx.y * 32;   // t
#pragma unroll
  for (int i = 0; i < 32; i += 8)
    tile[ty + i][tx] = in[(size_t)(r0 + ty + i) * KVDIM + c0 + tx];
  __syncthreads();
#pragma unroll
  for (int i = 0; i < 32; i += 8)
    out[(size_t)(c0 + ty + i) * T_LEN + r0 + tx] = tile[tx][ty + i];
}

// ---------------------------------------------------------------------------
// bf16 MFMA GEMM core (m97 structure). Caller must declare LDS buffers
// Abuf/Bbuf (ushort, 128*32 each, 16B aligned) before invoking.
// ---------------------------------------------------------------------------
#define GEMM_CORE(KDIM, APTR, BPTR)                                           \
  const int tid = threadIdx.x;                                                \
  const int wave = tid >> 6;                                                  \
  const int lane = tid & 63;                                                  \
  const int lo = lane & 15;                                                   \
  const int quad = lane >> 4;                                                 \
  const int m0 = blockIdx.y * 128;                                            \
  const int n0 = blockIdx.x * 128;                                            \
  const int mw = (wave & 1) * 64;                                             \
  const int nw = (wave >> 1) * 64;                                            \
  f32x4 acc[4][4];                                                            \
  _Pragma("unroll") for (int i = 0; i < 4; ++i)                               \
      _Pragma("unroll") for (int j = 0; j < 4; ++j)                           \
          acc[i][j] = {0.f, 0.f, 0.f, 0.f};                                   \
  for (int kt = 0; kt < (KDIM); kt += 32) {                                   \
    _Pragma("unroll") for (int j = 0; j < 2; ++j) {                           \
      const int c = wave * 128 + j * 64 + lane;                               \
      const int row = c >> 2;                                                 \
      const int colb = (c & 3) << 4;                                          \
      const int ldsOff = (wave * 128 + j * 64) * 16;                          \
      load_lds16((const char*)(APTR) + ((size_t)(m0 + row) * (KDIM) + kt) * 2 + colb, \
                 (char*)Abuf + ldsOff);                                       \
      load_lds16((const char*)(BPTR) + ((size_t)(n0 + row) * (KDIM) + kt) * 2 + colb, \
                 (char*)Bbuf + ldsOff);                                       \
    }                                                                         \
    __syncthreads();                                                          \
    short8 af[4], bfr[4];                                                     \
    _Pragma("unroll") for (int mt = 0; mt < 4; ++mt)                          \
        af[mt] = *(const short8*)&Abuf[(mw + mt * 16 + lo) * 32 + quad * 8];  \
    _Pragma("unroll") for (int nt = 0; nt < 4; ++nt)                          \
        bfr[nt] = *(const short8*)&Bbuf[(nw + nt * 16 + lo) * 32 + quad * 8]; \
    _Pragma("unroll") for (int mt = 0; mt < 4; ++mt)                          \
        _Pragma("unroll") for (int nt = 0; nt < 4; ++nt)                      \
            acc[mt][nt] = __builtin_amdgcn_mfma_f32_16x16x32_bf16(            \
                af[mt], bfr[nt], acc[mt][nt], 0, 0, 0);                       \
    __syncthreads();                                                          \
  }

// Plain fp32-out GEMM (used for W_o)
__global__ __launch_bounds__(256) void gemm_bf16(
    const ushort* __restrict__ A, const ushort* __restrict__ Bt,
    float* __restrict__ C, int N, int K) {
  __shared__ ushort Abuf[128 * 32];
  __shared__ ushort Bbuf[128 * 32];
  GEMM_CORE(K, A, Bt)
#pragma unroll
  for (int mt = 0; mt < 4; ++mt) {
    const int r0 = m0 + mw + mt * 16 + quad * 4;
#pragma unroll
    for (int nt = 0; nt < 4; ++nt) {
      const int cc = n0 + nw + nt * 16 + lo;
#pragma unroll
      for (int r = 0; r < 4; ++r)
        C[(size_t)(r0 + r) * N + cc] = acc[mt][nt][r];
    }
  }
}

// ---------------------------------------------------------------------------
// Unified projection GEMM: A[8192][1536] @ Wall[3072][1536]^T.
// Column sections: [0,1536) q (rope, bf16) | [1536,1920) k (rope, bf16) |
// [1920,2304) v (bf16) | [2304,2688) kg (rope, f32) | [2688,3072) vg (f32).
// RoPE coefs staged in LDS (overlaying Abuf/Bbuf, dead after K-loop).
// ---------------------------------------------------------------------------
__global__ __launch_bounds__(256) void gemm_proj(
    const ushort* __restrict__ A, const ushort* __restrict__ Wall,
    ushort* __restrict__ q_bf, ushort* __restrict__ k_bf,
    ushort* __restrict__ v_bf, float* __restrict__ kg,
    float* __restrict__ vg, const float* __restrict__ cosf,
    const float* __restrict__ sinf, const int* __restrict__ pid) {
  __shared__ char smem[25088];
  ushort* Abuf = (ushort*)smem;
  ushort* Bbuf = (ushort*)(smem + 8192);
  unsigned int* CoefS = (unsigned int*)smem;      // [128][48] packed cos|sin
  int* PidS = (int*)(smem + 24576);               // [128]

  GEMM_CORE(DMODEL, A, Wall)

  // Section routing (block-uniform)
  const int xb = blockIdx.x;
  int sec, cbase;
  if (xb < 12)      { sec = 0; cbase = 0; }
  else if (xb < 15) { sec = 1; cbase = 1536; }
  else if (xb < 18) { sec = 2; cbase = 1920; }
  else if (xb < 21) { sec = 3; cbase = 2304; }
  else              { sec = 4; cbase = 2688; }
  const bool doRope = (sec == 0) || (sec == 1) || (sec == 3);

  // Stage pid + packed bf16 cos/sin coefs for this block's 128 rows.
  // Abuf/Bbuf are dead (all waves passed the final K-loop barrier).
  if (tid < 128) PidS[tid] = pid[m0 + tid];
  __syncthreads();
  if (doRope) {
#pragma unroll
    for (int j = 0; j < 24; ++j) {
      const int idx = j * 256 + tid;          // 0..6143
      const int rr = idx / 48;
      const int ff = idx - rr * 48;
      const int pos = PidS[rr];
      const float c = cosf[(size_t)pos * NFREQ + ff];
      const float s = sinf[(size_t)pos * NFREQ + ff];
      CoefS[idx] = (unsigned int)f2bf(c) | ((unsigned int)f2bf(s) << 16);
    }
  }
  __syncthreads();

#pragma unroll
  for (int mt = 0; mt < 4; ++mt) {
    const int lr0 = mw + mt * 16 + quad * 4;   // local row 0..127
#pragma unroll
    for (int nt = 0; nt < 4; ++nt) {
      const int cc = n0 + nw + nt * 16 + lo;
      const int col = cc - cbase;
      const int d = col % HD;
      const int fi = d >> 1;
#pragma unroll
      for (int r = 0; r < 4; ++r) {
        const int lr = lr0 + r;
        float v = acc[mt][nt][r];
        if (doRope) {
          const unsigned int pk = CoefS[lr * 48 + fi];
          const float co = bf2f((ushort)(pk & 0xFFFF));
          const float si = bf2f((ushort)(pk >> 16));
          const float pe = __shfl_xor(v, 1);
          v = (d & 1) ? fmaf(pe, si, v * co) : fmaf(v, co, -pe * si);
        }
        const int t = m0 + lr;
        if (sec == 0)      q_bf[(size_t)t * DMODEL + col] = f2bf(v);
        else if (sec == 1) k_bf[(size_t)t * KVDIM + col] = f2bf(v);
        else if (sec == 2) v_bf[(size_t)t * KVDIM + col] = f2bf(v);
        else if (sec == 3) kg[(size_t)t * KVDIM + col] = v;
        else               vg[(size_t)t * KVDIM + col] = v;
      }
    }
  }
}

// ---------------------------------------------------------------------------
// qg row 0: zero + split-k atomics
// ---------------------------------------------------------------------------
__global__ void qg0_zero(float* __restrict__ qg0) {
  qg0[blockIdx.x * 256 + threadIdx.x] = 0.f;
}
__global__ __launch_bounds__(256) void qg0_split(
    const float* __restrict__ x, const float* __restrict__ W,
    float* __restrict__ qg0) {
  const int j = blockIdx.x * 256 + threadIdx.x;
  const int k0 = blockIdx.y * 128;
  float acc = 0.f;
#pragma unroll 8
  for (int k = k0; k < k0 + 128; ++k)
    acc = fmaf(x[k], W[(size_t)k * DMODEL + j], acc);
  atomicAdd(&qg0[j], acc);
}

// ---------------------------------------------------------------------------
// Local attention v4: MFMA bf16 flash tiles; V staged from pre-transposed
// Vt_g[KVDIM][T] via global_load_lds.
// ---------------------------------------------------------------------------
__global__ __launch_bounds__(256) void local_attn_v4(
    const ushort* __restrict__ qbf, const ushort* __restrict__ kbf,
    const ushort* __restrict__ vtg, const float* __restrict__ kg,
    const float* __restrict__ vg, ushort* __restrict__ obf) {
  __shared__ ushort Qb[3 * 64 * 32];
  __shared__ ushort Kb[3 * 64 * 32];
  __shared__ ushort Vt[2 * 96 * 32];   // panel kp: [96 dims][32 keys]
  __shared__ ushort Pb[4][2 * 16 * 32];
  __shared__ float Kg0[HD];
  __shared__ float Vg0[HD];

  const int t0 = blockIdx.x * 64;
  const int h  = blockIdx.y;
  const int kh = h >> 2;
  const int tid = threadIdx.x;
  const int w    = tid >> 6;
  const int lane = tid & 63;
  const int lo   = lane & 15;
  const int quad = lane >> 4;

  {
    const int rem = w * 64 + lane;
    const int row = rem >> 2;
    const int sub = (rem & 3) * 8;
#pragma unroll
    for (int j = 0; j < 3; ++j) {
      load_lds16(qbf + (size_t)(t0 + row) * DMODEL + h * HD + j * 32 + sub,
                 (char*)Qb + (j * 256 + w * 64) * 16);
    }
  }
  if (tid < HD) {
    Kg0[tid] = kg[kh * HD + tid];   // row 0 (rope at pos 0 = identity)
    Vg0[tid] = vg[kh * HD + tid];
  }

  f32x4 O[6];
#pragma unroll
  for (int i = 0; i < 6; ++i) O[i] = {0.f, 0.f, 0.f, 0.f};
  float m_run[4], l_run[4];
#pragma unroll
  for (int r = 0; r < 4; ++r) { m_run[r] = -1e30f; l_run[r] = 0.f; }

  __syncthreads();

  for (int ti = 0; ti < 5; ++ti) {
    const int kb = t0 - W2 + ti * 64;
    if (kb < 0) continue;

    {
      const int rem = w * 64 + lane;
      const int row = rem >> 2;
      const int sub = (rem & 3) * 8;
#pragma unroll
      for (int j = 0; j < 3; ++j) {
        load_lds16(kbf + (size_t)(kb + row) * KVDIM + kh * HD + j * 32 + sub,
                   (char*)Kb + (j * 256 + w * 64) * 16);
      }
#pragma unroll
      for (int j = 0; j < 3; ++j) {
        const int cc = j * 256 + w * 64 + lane;
        const int half = cc / 384;
        const int rm2 = cc - half * 384;
        const int dd = rm2 >> 2;
        const int sb = (rm2 & 3) * 8;
        load_lds16(vtg + (size_t)(kh * HD + dd) * T_LEN + kb + half * 32 + sb,
                   (char*)Vt + (j * 256 + w * 64) * 16);
      }
    }
    __syncthreads();

    short8 af[3];
#pragma unroll
    for (int p = 0; p < 3; ++p)
      af[p] = *(const short8*)&Qb[p * 2048 + (w * 16 + lo) * 32 + quad * 8];
    f32x4 s4[4];
#pragma unroll
    for (int nt = 0; nt < 4; ++nt) s4[nt] = {0.f, 0.f, 0.f, 0.f};
#pragma unroll
    for (int nt = 0; nt < 4; ++nt)
#pragma unroll
      for (int p = 0; p < 3; ++p) {
        const short8 bf8 =
            *(const short8*)&Kb[p * 2048 + (nt * 16 + lo) * 32 + quad * 8];
        s4[nt] = __builtin_amdgcn_mfma_f32_16x16x32_bf16(af[p], bf8, s4[nt], 0, 0, 0);
      }

    float alpha[4];
#pragma unroll
    for (int r = 0; r < 4; ++r) {
      const int tq = t0 + w * 16 + quad * 4 + r;
      float sv[4], rm = -1e30f;
#pragma unroll
      for (int nt = 0; nt < 4; ++nt) {
        const int p = kb + nt * 16 + lo;
        const bool ok = (p >= 1) && (p <= tq) && (p + W2 >= tq);
        sv[nt] = ok ? s4[nt][r] * SCALE : -1e30f;
        rm = fmaxf(rm, sv[nt]);
      }
#pragma unroll
      for (int mo = 1; mo < 16; mo <<= 1) rm = fmaxf(rm, __shfl_xor(rm, mo));
      const float m_new = fmaxf(m_run[r], rm);
      float psum = 0.f;
#pragma unroll
      for (int nt = 0; nt < 4; ++nt) {
        const float pv = (sv[nt] > -1e29f) ? __expf(sv[nt] - m_new) : 0.f;
        Pb[w][(nt >> 1) * 512 + (quad * 4 + r) * 32 + (nt & 1) * 16 + lo] = f2bf(pv);
        psum += pv;
      }
#pragma unroll
      for (int mo = 1; mo < 16; mo <<= 1) psum += __shfl_xor(psum, mo);
      alpha[r] = __expf(m_run[r] - m_new);
      l_run[r] = l_run[r] * alpha[r] + psum;
      m_run[r] = m_new;
    }

#pragma unroll
    for (int nt6 = 0; nt6 < 6; ++nt6)
#pragma unroll
      for (int r = 0; r < 4; ++r) O[nt6][r] *= alpha[r];

    short8 pa[2];
#pragma unroll
    for (int kp = 0; kp < 2; ++kp)
      pa[kp] = *(const short8*)&Pb[w][kp * 512 + lo * 32 + quad * 8];
#pragma unroll
    for (int nt6 = 0; nt6 < 6; ++nt6)
#pragma unroll
      for (int kp = 0; kp < 2; ++kp) {
        const short8 vb8 =
            *(const short8*)&Vt[kp * 3072 + (nt6 * 16 + lo) * 32 + quad * 8];
        O[nt6] = __builtin_amdgcn_mfma_f32_16x16x32_bf16(pa[kp], vb8, O[nt6], 0, 0, 0);
      }
    __syncthreads();
  }

  float sg[4];
#pragma unroll
  for (int r = 0; r < 4; ++r) {
    const int row = w * 16 + quad * 4 + r;
    float part = 0.f;
#pragma unroll
    for (int i = 0; i < 6; ++i) {
      const int d = lo * 6 + i;
      part += bf2f(Qb[(d >> 5) * 2048 + row * 32 + (d & 31)]) * Kg0[d];
    }
#pragma unroll
    for (int mo = 1; mo < 16; mo <<= 1) part += __shfl_xor(part, mo);
    sg[r] = part * SCALE;
  }
#pragma unroll
  for (int r = 0; r < 4; ++r) {
    const float m_new = fmaxf(m_run[r], sg[r]);
    const float al = __expf(m_run[r] - m_new);
    const float pg = __expf(sg[r] - m_new);
    const float inv = 1.0f / (l_run[r] * al + pg);
    ushort* dst = obf + (size_t)(t0 + w * 16 + quad * 4 + r) * DMODEL + h * HD;
#pragma unroll
    for (int nt6 = 0; nt6 < 6; ++nt6) {
      const int d = nt6 * 16 + lo;
      dst[d] = f2bf((O[nt6][r] * al + pg * Vg0[d]) * inv);
    }
  }
}

// ---------------------------------------------------------------------------
// Global row, split-k partials: grid (NH, NGB); 256 keys per block.
// ---------------------------------------------------------------------------
__global__ __launch_bounds__(256) void global_attn_part(
    const float* __restrict__ qg0, const float* __restrict__ kg,
    const float* __restrict__ vg, float* __restrict__ gM,
    float* __restrict__ gL, float* __restrict__ gO) {
  const int h = blockIdx.x;
  const int g = blockIdx.y;
  const int kh = h >> 2;
  const int tid = threadIdx.x;
  const int wv = tid >> 6;
  __shared__ float q[HD];
  __shared__ float sp[256];
  __shared__ float red[4];
  __shared__ float od[2][HD];

  if (tid < HD) q[tid] = qg0[h * HD + tid];
  __syncthreads();

  const int key = g * 256 + tid;
  const float* kp = kg + (size_t)key * KVDIM + kh * HD;
  float d = 0.f;
#pragma unroll
  for (int j = 0; j < 24; ++j) {
    const f32x4 kv = *(const f32x4*)(kp + j * 4);
    const f32x4 qv = *(const f32x4*)(&q[j * 4]);
    d += qv[0] * kv[0] + qv[1] * kv[1] + qv[2] * kv[2] + qv[3] * kv[3];
  }
  d *= SCALE;

  float pm = d;
#pragma unroll
  for (int off = 32; off > 0; off >>= 1) pm = fmaxf(pm, __shfl_down(pm, off));
  if ((tid & 63) == 0) red[wv] = pm;
  __syncthreads();
  const float M = fmaxf(fmaxf(red[0], red[1]), fmaxf(red[2], red[3]));
  __syncthreads();
  const float p = __expf(d - M);
  sp[tid] = p;
  float ps = p;
#pragma unroll
  for (int off = 32; off > 0; off >>= 1) ps += __shfl_down(ps, off);
  if ((tid & 63) == 0) red[wv] = ps;
  __syncthreads();
  const float L = red[0] + red[1] + red[2] + red[3];

  if (tid < 192) {
    const int grp = tid >= HD;
    const int dd = tid - grp * HD;
    float acc = 0.f;
    const float* vp = vg + (size_t)(g * 256 + grp * 128) * KVDIM + kh * HD + dd;
#pragma unroll 4
    for (int i = 0; i < 128; ++i)
      acc = fmaf(sp[grp * 128 + i], vp[(size_t)i * KVDIM], acc);
    od[grp][dd] = acc;
  }
  __syncthreads();
  if (tid < HD) gO[((size_t)h * NGB + g) * HD + tid] = od[0][tid] + od[1][tid];
  if (tid == 0) { gM[h * NGB + g] = M; gL[h * NGB + g] = L; }
}

__global__ void global_attn_comb(const float* __restrict__ gM,
                                 const float* __restrict__ gL,
                                 const float* __restrict__ gO,
                                 ushort* __restrict__ obf) {
  const int h = blockIdx.x;
  const int d = threadIdx.x;
  if (d >= HD) return;
  float M = -1e30f;
  for (int g = 0; g < NGB; ++g) M = fmaxf(M, gM[h * NGB + g]);
  float L = 0.f, O = 0.f;
  for (int g = 0; g < NGB; ++g) {
    const float e = __expf(gM[h * NGB + g] - M);
    L += gL[h * NGB + g] * e;
    O += gO[((size_t)h * NGB + g) * HD + d] * e;
  }
  obf[h * HD + d] = f2bf(O / L);
}

// ---------------------------------------------------------------------------
// Launch
// ---------------------------------------------------------------------------
extern "C" void kernel_launch(void* const* d_in, const int* in_sizes, int n_in,
                              void* d_out, int out_size, void* d_ws, size_t ws_size,
                              hipStream_t stream) {
  const float* x     = (const float*)d_in[0];
  const float* cosf  = (const float*)d_in[1];
  const float* sinf  = (const float*)d_in[2];
  const int*   pid   = (const int*)d_in[3];
  const float* W_qs  = (const float*)d_in[4];
  const float* W_ks  = (const float*)d_in[5];
  const float* W_vs  = (const float*)d_in[6];
  const float* W_qg  = (const float*)d_in[7];
  const float* W_kg  = (const float*)d_in[8];
  const float* W_vg  = (const float*)d_in[9];
  const float* W_o   = (const float*)d_in[10];
  float* out = (float*)d_out;

  char* p = (char*)d_ws;
  auto alloc = [&](size_t bytes) { char* r = p; p += (bytes + 255) & ~(size_t)255; return r; };
  float*  kg     = (float*)alloc((size_t)T_LEN * KVDIM * 4);
  float*  vg     = (float*)alloc((size_t)T_LEN * KVDIM * 4);
  float*  qg0    = (float*)alloc(DMODEL * 4);
  ushort* x_bf   = (ushort*)alloc((size_t)T_LEN * DMODEL * 2);
  ushort* q_bf   = (ushort*)alloc((size_t)T_LEN * DMODEL * 2);
  ushort* attnbf = (ushort*)alloc((size_t)T_LEN * DMODEL * 2);
  ushort* k_bf   = (ushort*)alloc((size_t)T_LEN * KVDIM * 2);
  ushort* v_bf   = (ushort*)alloc((size_t)T_LEN * KVDIM * 2);
  ushort* vt_g   = (ushort*)alloc((size_t)KVDIM * T_LEN * 2);
  ushort* Wall   = (ushort*)alloc((size_t)NPROJ * DMODEL * 2);  // q + 4 KV
  ushort* Wo_t   = (ushort*)alloc((size_t)DMODEL * DMODEL * 2);
  float*  gM     = (float*)alloc((size_t)NH * NGB * 4);
  float*  gL     = (float*)alloc((size_t)NH * NGB * 4);
  float*  gO     = (float*)alloc((size_t)NH * NGB * HD * 4);

  const dim3 blk(256);
  const int nX4 = (T_LEN * DMODEL) / 4;

  // bf16 conversions / weight transposes (packed into Wall)
  convert_bf16<<<(nX4 + 255) / 256, blk, 0, stream>>>(x, x_bf, nX4);
  transpose_bf16<<<dim3(DMODEL / 32, DMODEL / 32), blk, 0, stream>>>(W_qs, Wall, DMODEL, DMODEL);
  transpose_bf16<<<dim3(DMODEL / 32, DMODEL / 32), blk, 0, stream>>>(W_o,  Wo_t, DMODEL, DMODEL);
  transpose_bf16_kv4<<<dim3(KVDIM / 32, DMODEL / 32, 4), blk, 0, stream>>>(
      W_ks, W_vs, W_kg, W_vg, Wall + (size_t)DMODEL * DMODEL);

  // Unified projection GEMM with fused RoPE/bf16 epilogue (LDS-staged coefs)
  gemm_proj<<<dim3(NPROJ / 128, T_LEN / 128), blk, 0, stream>>>(
      x_bf, Wall, q_bf, k_bf, v_bf, kg, vg, cosf, sinf, pid);

  // qg row 0 (RoPE at pos 0 is identity -> skipped)
  qg0_zero<<<DMODEL / 256, blk, 0, stream>>>(qg0);
  qg0_split<<<dim3(DMODEL / 256, DMODEL / 128), blk, 0, stream>>>(x, W_qg, qg0);

  // V pre-transpose for local attention
  transpose_u16<<<dim3(KVDIM / 32, T_LEN / 32), blk, 0, stream>>>(v_bf, vt_g);

  // Attention
  local_attn_v4<<<dim3(T_LEN / 64, NH), blk, 0, stream>>>(
      q_bf, k_bf, vt_g, kg, vg, attnbf);
  global_attn_part<<<dim3(NH, NGB), blk, 0, stream>>>(qg0, kg, vg, gM, gL, gO);
  global_attn_comb<<<NH, dim3(128), 0, stream>>>(gM, gL, gO, attnbf);

  // Output projection
  gemm_bf16<<<dim3(DMODEL / 128, T_LEN / 128), blk, 0, stream>>>(
      attnbf, Wo_t, out, DMODEL, DMODEL);
}